// Round 1
// baseline (2978.415 us; speedup 1.0000x reference)
//
#include <hip/hip_runtime.h>

constexpr int N_NODES  = 500000;
constexpr int N_EDGES  = 8000000;
constexpr int N_GRAPHS = 25000;
constexpr int HID      = 19;

// ---------------- h = x @ w0 + b0 ----------------
template<int IN>
__global__ __launch_bounds__(256)
void proj_kernel(const float* __restrict__ x, const float* __restrict__ w,
                 const float* __restrict__ b, float* __restrict__ h) {
    __shared__ float ws[IN * HID + HID];
    for (int i = threadIdx.x; i < IN * HID + HID; i += 256)
        ws[i] = (i < IN * HID) ? w[i] : b[i - IN * HID];
    __syncthreads();
    int n = blockIdx.x * 256 + threadIdx.x;
    if (n >= N_NODES) return;
    float xr[IN];
    const float* xp = x + n * IN;
    #pragma unroll
    for (int i = 0; i < IN; ++i) xr[i] = xp[i];
    float* hp = h + n * HID;
    #pragma unroll
    for (int j = 0; j < HID; ++j) {
        float acc = ws[IN * HID + j];
        #pragma unroll
        for (int i = 0; i < IN; ++i) acc = fmaf(xr[i], ws[i * HID + j], acc);
        hp[j] = acc;
    }
}

// ---------------- agg[dst] += h[src], one thread per (edge, channel) ----------------
constexpr int EPB = 13;  // edges per 256-thread block (13*19 = 247 active lanes)
__global__ __launch_bounds__(256)
void scatter_kernel(const int* __restrict__ src, const int* __restrict__ dst,
                    const float* __restrict__ h, float* __restrict__ agg) {
    int tid = threadIdx.x;
    if (tid >= EPB * HID) return;
    int el = tid / HID;
    int ch = tid - el * HID;
    int e = blockIdx.x * EPB + el;
    if (e >= N_EDGES) return;
    int s = src[e];
    int d = dst[e];
    atomicAdd(&agg[d * HID + ch], h[s * HID + ch]);
}

// ---------------- out = relu(x@w1[:IN] + agg@w1[IN:] + b1 [+ x residual]) ----------------
template<int IN, bool RES>
__global__ __launch_bounds__(256)
void outfc_kernel(const float* __restrict__ x, const float* __restrict__ agg,
                  const float* __restrict__ w, const float* __restrict__ b,
                  float* __restrict__ out) {
    constexpr int WN = (IN + HID) * HID;
    __shared__ float ws[WN + HID];
    for (int i = threadIdx.x; i < WN + HID; i += 256)
        ws[i] = (i < WN) ? w[i] : b[i - WN];
    __syncthreads();
    int n = blockIdx.x * 256 + threadIdx.x;
    if (n >= N_NODES) return;
    float xr[IN], ar[HID];
    const float* xp = x + n * IN;
    #pragma unroll
    for (int i = 0; i < IN; ++i) xr[i] = xp[i];
    const float* ap = agg + n * HID;
    #pragma unroll
    for (int k = 0; k < HID; ++k) ar[k] = ap[k];
    float* op = out + n * HID;
    #pragma unroll
    for (int j = 0; j < HID; ++j) {
        float acc = ws[WN + j];
        #pragma unroll
        for (int i = 0; i < IN; ++i) acc = fmaf(xr[i], ws[i * HID + j], acc);
        #pragma unroll
        for (int k = 0; k < HID; ++k) acc = fmaf(ar[k], ws[(IN + k) * HID + j], acc);
        if (RES) acc += xr[j];
        op[j] = fmaxf(acc, 0.0f);
    }
}

// ---------------- pos[g] = index of last node with batch <= g (JAX cumsum(bincount)-1) ----------------
__global__ __launch_bounds__(256)
void pos_kernel(const int* __restrict__ batch, int* __restrict__ pos) {
    int i = blockIdx.x * 256 + threadIdx.x;
    if (i >= N_NODES) return;
    int b  = batch[i];
    int nb = (i == N_NODES - 1) ? N_GRAPHS : batch[i + 1];
    for (int g = b; g < nb; ++g) pos[g] = i;       // boundary node fills its run
    if (i == 0) {
        // graphs before batch[0]: cumsum-1 == -1 -> JAX wraps to last node
        for (int g = 0; g < b; ++g) pos[g] = N_NODES - 1;
    }
}

// ---------------- g = h[pos]; out = relu(relu(g@wfc0+bfc0)@wfc1+bfc1) ----------------
__global__ __launch_bounds__(256)
void readout_kernel(const float* __restrict__ h, const int* __restrict__ pos,
                    const float* __restrict__ w0, const float* __restrict__ b0,
                    const float* __restrict__ w1, const float* __restrict__ b1,
                    float* __restrict__ out) {
    __shared__ float ws[HID * 10 + 10 + 10 + 1];   // w0 | b0 | w1 | b1
    for (int i = threadIdx.x; i < 211; i += 256) {
        float v;
        if (i < 190)      v = w0[i];
        else if (i < 200) v = b0[i - 190];
        else if (i < 210) v = w1[i - 200];
        else              v = b1[0];
        ws[i] = v;
    }
    __syncthreads();
    int g = blockIdx.x * 256 + threadIdx.x;
    if (g >= N_GRAPHS) return;
    const float* hp = h + pos[g] * HID;
    float t[10];
    #pragma unroll
    for (int j = 0; j < 10; ++j) {
        float acc = ws[190 + j];
        #pragma unroll
        for (int i = 0; i < HID; ++i) acc = fmaf(hp[i], ws[i * 10 + j], acc);
        t[j] = fmaxf(acc, 0.0f);
    }
    float o = ws[210];
    #pragma unroll
    for (int j = 0; j < 10; ++j) o = fmaf(t[j], ws[200 + j], o);
    out[g] = fmaxf(o, 0.0f);
}

extern "C" void kernel_launch(void* const* d_in, const int* in_sizes, int n_in,
                              void* d_out, int out_size, void* d_ws, size_t ws_size,
                              hipStream_t stream) {
    const float* x    = (const float*)d_in[0];
    const int*   ei   = (const int*)d_in[1];
    const int*   batch= (const int*)d_in[2];
    const float* w0_1 = (const float*)d_in[3];
    const float* b0_1 = (const float*)d_in[4];
    const float* w1_1 = (const float*)d_in[5];
    const float* b1_1 = (const float*)d_in[6];
    const float* w0_2 = (const float*)d_in[7];
    const float* b0_2 = (const float*)d_in[8];
    const float* w1_2 = (const float*)d_in[9];
    const float* b1_2 = (const float*)d_in[10];
    const float* w0_3 = (const float*)d_in[11];
    const float* b0_3 = (const float*)d_in[12];
    const float* w1_3 = (const float*)d_in[13];
    const float* b1_3 = (const float*)d_in[14];
    const float* wfc0 = (const float*)d_in[15];
    const float* bfc0 = (const float*)d_in[16];
    const float* wfc1 = (const float*)d_in[17];
    const float* bfc1 = (const float*)d_in[18];

    const int* src = ei;            // edge_index[0]
    const int* dst = ei + N_EDGES;  // edge_index[1]

    char* ws = (char*)d_ws;
    const size_t NB = (size_t)N_NODES * HID * sizeof(float);  // 38 MB
    float* BUF_A = (float*)(ws);
    float* BUF_B = (float*)(ws + NB);
    float* AGG   = (float*)(ws + 2 * NB);
    int*   pos   = (int*)(ws + 3 * NB);

    dim3 blk(256);
    int gridN = (N_NODES + 255) / 256;
    int gridE = (N_EDGES + EPB - 1) / EPB;
    int gridG = (N_GRAPHS + 255) / 256;

    pos_kernel<<<gridN, blk, 0, stream>>>(batch, pos);

    // ---- Layer 1 (IN=11, no residual): out1 -> BUF_B ----
    hipMemsetAsync(AGG, 0, NB, stream);
    proj_kernel<11><<<gridN, blk, 0, stream>>>(x, w0_1, b0_1, BUF_A);
    scatter_kernel<<<gridE, blk, 0, stream>>>(src, dst, BUF_A, AGG);
    outfc_kernel<11, false><<<gridN, blk, 0, stream>>>(x, AGG, w1_1, b1_1, BUF_B);

    // ---- Layer 2 (IN=19, residual): out2 -> BUF_A ----
    hipMemsetAsync(AGG, 0, NB, stream);
    proj_kernel<19><<<gridN, blk, 0, stream>>>(BUF_B, w0_2, b0_2, BUF_A);
    scatter_kernel<<<gridE, blk, 0, stream>>>(src, dst, BUF_A, AGG);
    outfc_kernel<19, true><<<gridN, blk, 0, stream>>>(BUF_B, AGG, w1_2, b1_2, BUF_A);

    // ---- Layer 3 (IN=19, residual): out3 -> BUF_B ----
    hipMemsetAsync(AGG, 0, NB, stream);
    proj_kernel<19><<<gridN, blk, 0, stream>>>(BUF_A, w0_3, b0_3, BUF_B);
    scatter_kernel<<<gridE, blk, 0, stream>>>(src, dst, BUF_B, AGG);
    outfc_kernel<19, true><<<gridN, blk, 0, stream>>>(BUF_A, AGG, w1_3, b1_3, BUF_B);

    // ---- Readout ----
    readout_kernel<<<gridG, blk, 0, stream>>>(BUF_B, pos, wfc0, bfc0, wfc1, bfc1,
                                              (float*)d_out);
}

// Round 2
// 1724.810 us; speedup vs baseline: 1.7268x; 1.7268x over previous
//
#include <hip/hip_runtime.h>

constexpr int N_NODES  = 500000;
constexpr int N_EDGES  = 8000000;
constexpr int N_GRAPHS = 25000;
constexpr int HID      = 19;
constexpr int NBLK     = (N_NODES + 255) / 256;   // 1954 blocks over nodes
constexpr int NPB      = 13;                       // nodes per 256-thread block (13*19=247)

// ---------------- CSR build: histogram ----------------
__global__ __launch_bounds__(256)
void hist_kernel(const int* __restrict__ dst, int* __restrict__ cnt) {
    int e = blockIdx.x * 256 + threadIdx.x;
    if (e < N_EDGES) atomicAdd(&cnt[dst[e]], 1);
}

// ---------------- CSR build: per-block sums ----------------
__global__ __launch_bounds__(256)
void blocksum_kernel(const int* __restrict__ cnt, int* __restrict__ bsum) {
    __shared__ int sh[256];
    int i = blockIdx.x * 256 + threadIdx.x;
    sh[threadIdx.x] = (i < N_NODES) ? cnt[i] : 0;
    __syncthreads();
    for (int off = 128; off > 0; off >>= 1) {
        if (threadIdx.x < off) sh[threadIdx.x] += sh[threadIdx.x + off];
        __syncthreads();
    }
    if (threadIdx.x == 0) bsum[blockIdx.x] = sh[0];
}

// ---------------- CSR build: scan block sums (exclusive), NBLK<=2048 ----------------
__global__ __launch_bounds__(1024)
void scanb_kernel(const int* __restrict__ bsum, int* __restrict__ boff) {
    __shared__ int sh[2048];
    int t = threadIdx.x;
    sh[t]        = (t        < NBLK) ? bsum[t]        : 0;
    sh[t + 1024] = (t + 1024 < NBLK) ? bsum[t + 1024] : 0;
    for (int off = 1; off < 2048; off <<= 1) {
        __syncthreads();
        int a = (t        >= off) ? sh[t - off]        : 0;
        int b = (t + 1024 >= off) ? sh[t + 1024 - off] : 0;
        __syncthreads();
        sh[t]        += a;
        sh[t + 1024] += b;
    }
    __syncthreads();
    if (t < NBLK)        boff[t]        = (t == 0) ? 0 : sh[t - 1];
    if (t + 1024 < NBLK) boff[t + 1024] = sh[t + 1023];
}

// ---------------- CSR build: offsets + cursor ----------------
__global__ __launch_bounds__(256)
void offsets_kernel(const int* __restrict__ cnt, const int* __restrict__ boff,
                    int* __restrict__ offsets, int* __restrict__ cursor) {
    __shared__ int sh[256];
    int t = threadIdx.x;
    int i = blockIdx.x * 256 + t;
    int v = (i < N_NODES) ? cnt[i] : 0;
    sh[t] = v;
    for (int off = 1; off < 256; off <<= 1) {
        __syncthreads();
        int a = (t >= off) ? sh[t - off] : 0;
        __syncthreads();
        sh[t] += a;
    }
    __syncthreads();
    if (i < N_NODES) {
        int excl = boff[blockIdx.x] + sh[t] - v;   // exclusive scan
        offsets[i] = excl;
        cursor[i]  = excl;
    }
    if (i == 0) offsets[N_NODES] = N_EDGES;
}

// ---------------- CSR build: fill sorted-by-dst src lists ----------------
__global__ __launch_bounds__(256)
void fill_kernel(const int* __restrict__ src, const int* __restrict__ dst,
                 int* __restrict__ cursor, int* __restrict__ csr) {
    int e = blockIdx.x * 256 + threadIdx.x;
    if (e < N_EDGES) {
        int p = atomicAdd(&cursor[dst[e]], 1);
        csr[p] = src[e];
    }
}

// ---------------- combined weights: wc = w0 @ w1[IN:], db = b0 @ w1[IN:] ----------------
__global__ __launch_bounds__(256)
void weights_kernel(const float* w0_1, const float* b0_1, const float* w1_1,
                    const float* w0_2, const float* b0_2, const float* w1_2,
                    const float* w0_3, const float* b0_3, const float* w1_3,
                    float* __restrict__ out) {   // 3 layers * 380 floats (361 wc + 19 db)
    const float *w0, *b0, *w1; int IN;
    if (blockIdx.x == 0)      { w0 = w0_1; b0 = b0_1; w1 = w1_1; IN = 11; }
    else if (blockIdx.x == 1) { w0 = w0_2; b0 = b0_2; w1 = w1_2; IN = 19; }
    else                      { w0 = w0_3; b0 = b0_3; w1 = w1_3; IN = 19; }
    __shared__ float sw0[19 * 19], sw1b[19 * 19], sb0[19];
    int t = threadIdx.x;
    for (int i = t; i < IN * 19; i += 256) sw0[i]  = w0[i];
    for (int i = t; i < 19 * 19; i += 256) sw1b[i] = w1[IN * 19 + i];
    if (t < 19) sb0[t] = b0[t];
    __syncthreads();
    float* o = out + blockIdx.x * 380;
    for (int idx = t; idx < IN * 19; idx += 256) {
        int i = idx / 19, j = idx - 19 * (idx / 19);
        float s = 0.f;
        #pragma unroll
        for (int k = 0; k < 19; ++k) s = fmaf(sw0[i * 19 + k], sw1b[k * 19 + j], s);
        o[idx] = s;
    }
    if (t < 19) {
        float s = 0.f;
        #pragma unroll
        for (int k = 0; k < 19; ++k) s = fmaf(sb0[k], sw1b[k * 19 + t], s);
        o[361 + t] = s;
    }
}

// ---------------- fused layer: out = relu(x@w1a + (S@x)@wc + deg*db + b1 [+ x]) ----------------
template<int IN, bool RES>
__global__ __launch_bounds__(256)
void fused_layer(const float* __restrict__ x, const int* __restrict__ csr,
                 const int* __restrict__ offsets,
                 const float* __restrict__ w1, const float* __restrict__ b1,
                 const float* __restrict__ wcdb, float* __restrict__ out) {
    __shared__ float sw1a[IN * 19], swc[IN * 19], sdb[19], sb1[19];
    __shared__ float shx[NPB][19], shs[NPB][19];
    int t = threadIdx.x;
    for (int i = t; i < IN * 19; i += 256) sw1a[i] = w1[i];
    for (int i = t; i < IN * 19; i += 256) swc[i]  = wcdb[i];
    if (t < 19) { sdb[t] = wcdb[361 + t]; sb1[t] = b1[t]; }
    __syncthreads();
    int g = t / 19, c = t - g * 19;
    int n = blockIdx.x * NPB + g;
    bool active = (t < NPB * 19) && (n < N_NODES);
    int o0 = 0, o1 = 0;
    if (active) {
        o0 = offsets[n]; o1 = offsets[n + 1];
        float xr = 0.f, acc = 0.f;
        if (c < IN) {
            xr = x[(size_t)n * IN + c];
            int i = o0;
            for (; i + 1 < o1; i += 2) {
                int s0 = csr[i], s1 = csr[i + 1];
                acc += x[(size_t)s0 * IN + c] + x[(size_t)s1 * IN + c];
            }
            if (i < o1) acc += x[(size_t)csr[i] * IN + c];
        }
        shx[g][c] = xr; shs[g][c] = acc;
    }
    __syncthreads();
    if (active) {
        float v = sb1[c] + (float)(o1 - o0) * sdb[c];
        #pragma unroll
        for (int i = 0; i < IN; ++i) v = fmaf(shx[g][i], sw1a[i * 19 + c], v);
        #pragma unroll
        for (int i = 0; i < IN; ++i) v = fmaf(shs[g][i], swc[i * 19 + c], v);
        if (RES) v += shx[g][c];
        out[(size_t)n * 19 + c] = fmaxf(v, 0.f);
    }
}

// ---------------- pos[g] = last node index of graph g ----------------
__global__ __launch_bounds__(256)
void pos_kernel(const int* __restrict__ batch, int* __restrict__ pos) {
    int i = blockIdx.x * 256 + threadIdx.x;
    if (i >= N_NODES) return;
    int b  = batch[i];
    int nb = (i == N_NODES - 1) ? N_GRAPHS : batch[i + 1];
    for (int g = b; g < nb; ++g) pos[g] = i;
    if (i == 0) {
        for (int g = 0; g < b; ++g) pos[g] = N_NODES - 1;   // JAX -1 wrap
    }
}

// ---------------- readout ----------------
__global__ __launch_bounds__(256)
void readout_kernel(const float* __restrict__ h, const int* __restrict__ pos,
                    const float* __restrict__ w0, const float* __restrict__ b0,
                    const float* __restrict__ w1, const float* __restrict__ b1,
                    float* __restrict__ out) {
    __shared__ float ws[HID * 10 + 10 + 10 + 1];
    for (int i = threadIdx.x; i < 211; i += 256) {
        float v;
        if (i < 190)      v = w0[i];
        else if (i < 200) v = b0[i - 190];
        else if (i < 210) v = w1[i - 200];
        else              v = b1[0];
        ws[i] = v;
    }
    __syncthreads();
    int g = blockIdx.x * 256 + threadIdx.x;
    if (g >= N_GRAPHS) return;
    const float* hp = h + (size_t)pos[g] * HID;
    float t[10];
    #pragma unroll
    for (int j = 0; j < 10; ++j) {
        float acc = ws[190 + j];
        #pragma unroll
        for (int i = 0; i < HID; ++i) acc = fmaf(hp[i], ws[i * 10 + j], acc);
        t[j] = fmaxf(acc, 0.0f);
    }
    float o = ws[210];
    #pragma unroll
    for (int j = 0; j < 10; ++j) o = fmaf(t[j], ws[200 + j], o);
    out[g] = fmaxf(o, 0.0f);
}

extern "C" void kernel_launch(void* const* d_in, const int* in_sizes, int n_in,
                              void* d_out, int out_size, void* d_ws, size_t ws_size,
                              hipStream_t stream) {
    const float* x     = (const float*)d_in[0];
    const int*   ei    = (const int*)d_in[1];
    const int*   batch = (const int*)d_in[2];
    const float* w0_1 = (const float*)d_in[3];
    const float* b0_1 = (const float*)d_in[4];
    const float* w1_1 = (const float*)d_in[5];
    const float* b1_1 = (const float*)d_in[6];
    const float* w0_2 = (const float*)d_in[7];
    const float* b0_2 = (const float*)d_in[8];
    const float* w1_2 = (const float*)d_in[9];
    const float* b1_2 = (const float*)d_in[10];
    const float* w0_3 = (const float*)d_in[11];
    const float* b0_3 = (const float*)d_in[12];
    const float* w1_3 = (const float*)d_in[13];
    const float* b1_3 = (const float*)d_in[14];
    const float* wfc0 = (const float*)d_in[15];
    const float* bfc0 = (const float*)d_in[16];
    const float* wfc1 = (const float*)d_in[17];
    const float* bfc1 = (const float*)d_in[18];

    const int* src = ei;            // edge_index[0]
    const int* dst = ei + N_EDGES;  // edge_index[1]

    char* ws = (char*)d_ws;
    size_t off = 0;
    auto alloc = [&](size_t bytes) { void* p = ws + off; off = (off + bytes + 511) & ~(size_t)511; return p; };
    float* BUF_A   = (float*)alloc((size_t)N_NODES * HID * 4);   // 38 MB
    float* BUF_B   = (float*)alloc((size_t)N_NODES * HID * 4);   // 38 MB
    int*   csr     = (int*)  alloc((size_t)N_EDGES * 4);         // 32 MB
    int*   offsets = (int*)  alloc(((size_t)N_NODES + 1) * 4);
    int*   cnt     = (int*)  alloc((size_t)N_NODES * 4);
    int*   cursor  = (int*)  alloc((size_t)N_NODES * 4);
    int*   bsum    = (int*)  alloc(2048 * 4);
    int*   boff    = (int*)  alloc(2048 * 4);
    int*   pos     = (int*)  alloc((size_t)N_GRAPHS * 4);
    float* wcdb    = (float*)alloc(3 * 380 * 4);

    dim3 blk(256);
    int gridN = (N_NODES + 255) / 256;    // 1954
    int gridE = (N_EDGES + 255) / 256;    // 31250
    int gridF = (N_NODES + NPB - 1) / NPB; // 38462
    int gridG = (N_GRAPHS + 255) / 256;

    weights_kernel<<<3, blk, 0, stream>>>(w0_1, b0_1, w1_1, w0_2, b0_2, w1_2,
                                          w0_3, b0_3, w1_3, wcdb);
    pos_kernel<<<gridN, blk, 0, stream>>>(batch, pos);

    // ---- CSR by destination (counting sort), once per call ----
    hipMemsetAsync(cnt, 0, (size_t)N_NODES * 4, stream);
    hist_kernel<<<gridE, blk, 0, stream>>>(dst, cnt);
    blocksum_kernel<<<NBLK, blk, 0, stream>>>(cnt, bsum);
    scanb_kernel<<<1, 1024, 0, stream>>>(bsum, boff);
    offsets_kernel<<<NBLK, blk, 0, stream>>>(cnt, boff, offsets, cursor);
    fill_kernel<<<gridE, blk, 0, stream>>>(src, dst, cursor, csr);

    // ---- 3 fused layers ----
    fused_layer<11, false><<<gridF, blk, 0, stream>>>(x,     csr, offsets, w1_1, b1_1, wcdb,       BUF_A);
    fused_layer<19, true ><<<gridF, blk, 0, stream>>>(BUF_A, csr, offsets, w1_2, b1_2, wcdb + 380, BUF_B);
    fused_layer<19, true ><<<gridF, blk, 0, stream>>>(BUF_B, csr, offsets, w1_3, b1_3, wcdb + 760, BUF_A);

    // ---- Readout ----
    readout_kernel<<<gridG, blk, 0, stream>>>(BUF_A, pos, wfc0, bfc0, wfc1, bfc1,
                                              (float*)d_out);
}